// Round 6
// baseline (109.068 us; speedup 1.0000x reference)
//
#include <hip/hip_runtime.h>
#include <hip/hip_bf16.h>

#define ATT_SCALE 0.17677669529663687f

typedef __attribute__((ext_vector_type(8))) short bf16x8;
typedef __attribute__((ext_vector_type(4))) short bf16x4;
typedef __attribute__((ext_vector_type(4))) float f32x4;
typedef __attribute__((ext_vector_type(16))) float f32x16;
typedef __attribute__((ext_vector_type(4))) int i32x4;

#define MFMA16(a, b, c) __builtin_amdgcn_mfma_f32_16x16x32_bf16(a, b, c, 0, 0, 0)
#define MFMA32(a, b, c) __builtin_amdgcn_mfma_f32_32x32x16_bf16(a, b, c, 0, 0, 0)

__device__ inline short f2b(float f) {
    return __builtin_bit_cast(short, __float2bfloat16(f));
}

__device__ inline float b2f(short u) {
    unsigned v = ((unsigned)(unsigned short)u) << 16;
    return __builtin_bit_cast(float, v);
}

__device__ inline bf16x8 cat4(bf16x4 a, bf16x4 b) {
    bf16x8 r;
    r[0] = a[0]; r[1] = a[1]; r[2] = a[2]; r[3] = a[3];
    r[4] = b[0]; r[5] = b[1]; r[6] = b[2]; r[7] = b[3];
    return r;
}

__device__ inline int packbf(float a, float b) {
    unsigned lo = (unsigned short)f2b(a);
    unsigned hi = (unsigned short)f2b(b);
    return (int)(lo | (hi << 16));
}

// ---------------------------------------------------------------------------
// K0a: w_qkv fp32 -> bf16
// ---------------------------------------------------------------------------
__global__ __launch_bounds__(256) void wconv_k(const float* __restrict__ w,
                                               short* __restrict__ wb) {
    int i0 = (blockIdx.x * 256 + threadIdx.x) * 8;
    float4 lo = *(const float4*)(w + i0);
    float4 hi = *(const float4*)(w + i0 + 4);
    bf16x8 o;
    o[0] = f2b(lo.x); o[1] = f2b(lo.y); o[2] = f2b(lo.z); o[3] = f2b(lo.w);
    o[4] = f2b(hi.x); o[5] = f2b(hi.y); o[6] = f2b(hi.z); o[7] = f2b(hi.w);
    *(bf16x8*)(wb + i0) = o;
}

// ---------------------------------------------------------------------------
// K0b: fused downsample + transpose + bf16: xt[b][n][c]
// ---------------------------------------------------------------------------
__global__ __launch_bounds__(256) void xt_k(const float* __restrict__ x,
                                            short* __restrict__ xt) {
    int b = blockIdx.y;
    int t = threadIdx.x;
    int n = blockIdx.x * 32 + (t >> 3);
    const float* xb = x + (size_t)b * 1048576 + (n >> 5) * 128 + (n & 31) * 2;
    short* dst = xt + ((size_t)b * 1024 + n) * 256;
#pragma unroll
    for (int it = 0; it < 4; ++it) {
        int c = (t & 7) * 8 + it * 64;
        bf16x8 o;
#pragma unroll
        for (int j = 0; j < 8; ++j) o[j] = f2b(xb[(size_t)(c + j) * 4096]);
        *(bf16x8*)(dst + c) = o;
    }
}

// ---------------------------------------------------------------------------
// K1: QKV MFMA GEMM (LDS-free main loop), epilogue transpose -> qt/kt/vv.
// ---------------------------------------------------------------------------
__global__ __launch_bounds__(256) void qkv_k(const short* __restrict__ wb,
                                             const short* __restrict__ xt,
                                             short* __restrict__ qt,
                                             short* __restrict__ kt,
                                             short* __restrict__ vv) {
    int b = blockIdx.z;
    int otile = blockIdx.y * 64;
    int ntile = blockIdx.x * 128;
    int t = threadIdx.x;
    int w = t >> 6, l = t & 63, g = l >> 4, li = l & 15;
    int oh = (w & 1) * 32, mh = (w >> 1) * 64;
    int o_base = otile + oh;
    int head = o_base / 96;
    int role = (o_base >> 5) % 3;  // 0=q 1=k 2=v
    size_t bh = (size_t)b * 8 + head;

    const short* arow = wb + (size_t)o_base * 256;
    const short* brow = xt + ((size_t)b * 1024 + ntile + mh) * 256;

    f32x4 zero = {0.f, 0.f, 0.f, 0.f};
    f32x4 acc[2][4];
#pragma unroll
    for (int og = 0; og < 2; ++og)
#pragma unroll
        for (int mg = 0; mg < 4; ++mg) acc[og][mg] = zero;

#pragma unroll
    for (int kc = 0; kc < 256; kc += 32) {
        bf16x8 af[2], bf_[4];
#pragma unroll
        for (int og = 0; og < 2; ++og)
            af[og] = *(const bf16x8*)(arow + (size_t)(og * 16 + li) * 256 + kc + 8 * g);
#pragma unroll
        for (int mg = 0; mg < 4; ++mg)
            bf_[mg] = *(const bf16x8*)(brow + (size_t)(mg * 16 + li) * 256 + kc + 8 * g);
#pragma unroll
        for (int og = 0; og < 2; ++og)
#pragma unroll
            for (int mg = 0; mg < 4; ++mg)
                acc[og][mg] = MFMA16(af[og], bf_[mg], acc[og][mg]);
    }

    __shared__ short Tl[4][32][64];
    short (*Tw)[64] = Tl[w];
    float sc = (role == 0) ? ATT_SCALE : 1.f;

#pragma unroll
    for (int og = 0; og < 2; ++og)
#pragma unroll
        for (int mg = 0; mg < 4; ++mg)
#pragma unroll
            for (int r = 0; r < 4; ++r) {
                int op = og * 16 + 4 * g + r;
                int qp = (op >> 3) & 3;
                Tw[op][(mg * 16 + li) ^ (qp << 4)] = f2b(acc[og][mg][r] * sc);
            }
    __syncthreads();

    if (role == 2) {
#pragma unroll
        for (int it = 0; it < 4; ++it) {
            int s = it * 64 + l;
            int o2 = s >> 3;
            int n8 = (s & 7) * 8;
            int q2 = (o2 >> 3) & 3;
            bf16x8 vo = *(const bf16x8*)&Tw[o2][n8 ^ (q2 << 4)];
            *(bf16x8*)(vv + ((size_t)bh * 32 + o2) * 1024 + ntile + mh + n8) = vo;
        }
    } else {
        short* dst = (role == 0) ? qt : kt;
#pragma unroll
        for (int it = 0; it < 4; ++it) {
            int s = it * 64 + l;
            int dq = (l & 3) * 8;
            int n = s >> 2;
            int q2 = dq >> 3;
            bf16x8 vo;
#pragma unroll
            for (int j = 0; j < 8; ++j)
                vo[j] = Tw[dq + j][n ^ (q2 << 4)];
            *(bf16x8*)(dst + ((size_t)bh * 1024 + ntile + mh + n) * 32 + dq) = vo;
        }
    }
}

// ---------------------------------------------------------------------------
// K2: attention with j-split (flash split-K, linear combine since no running
// max). Block = (itile 128, h, b*4+s); wave owns 32 q-rows x 256 j's.
// P lane-local via rho-map trick (round-5 verified). Emits UNNORMALIZED
// bf16 partial O (opart[s][b][c][n]) and fp32 partial denom lpart[s][bh][n].
// ---------------------------------------------------------------------------
__global__ __launch_bounds__(256) void attn_k(const short* __restrict__ qt,
                                              const short* __restrict__ kt,
                                              const short* __restrict__ vv,
                                              short* __restrict__ opart,
                                              float* __restrict__ lpart) {
    int z = blockIdx.z;
    int b = z >> 2, s = z & 3;
    int h = blockIdx.y;
    int bh = b * 8 + h;
    int w = threadIdx.x >> 6, l = threadIdx.x & 63;
    int il = l & 31, hi = l >> 5;
    int ibase = blockIdx.x * 128 + w * 32;
    int jbase = s * 256;

    const short* qtb = qt + (size_t)bh * 32768;
    const short* ktb = kt + (size_t)bh * 32768;
    const short* vb  = vv + (size_t)bh * 32768;

    bf16x8 qf0 = *(const bf16x8*)(qtb + (size_t)(ibase + il) * 32 + 8 * hi);
    bf16x8 qf1 = *(const bf16x8*)(qtb + (size_t)(ibase + il) * 32 + 16 + 8 * hi);

    f32x16 zero16 = {0.f,0.f,0.f,0.f,0.f,0.f,0.f,0.f,0.f,0.f,0.f,0.f,0.f,0.f,0.f,0.f};
    f32x16 oacc = zero16;
    float lrun = 0.f;

#pragma unroll 2
    for (int j0 = jbase; j0 < jbase + 256; j0 += 32) {
        bf16x8 kf0 = *(const bf16x8*)(ktb + (size_t)(j0 + il) * 32 + 8 * hi);
        bf16x8 kf1 = *(const bf16x8*)(ktb + (size_t)(j0 + il) * 32 + 16 + 8 * hi);
        f32x16 sc = MFMA32(kf0, qf0, zero16);
        sc = MFMA32(kf1, qf1, sc);

        float p[16];
#pragma unroll
        for (int r = 0; r < 16; ++r) {
            p[r] = __expf(sc[r]);
            lrun += p[r];
        }

        i32x4 fa, fb;
        fa[0] = packbf(p[0], p[1]);   fa[1] = packbf(p[2], p[3]);
        fa[2] = packbf(p[4], p[5]);   fa[3] = packbf(p[6], p[7]);
        fb[0] = packbf(p[8], p[9]);   fb[1] = packbf(p[10], p[11]);
        fb[2] = packbf(p[12], p[13]); fb[3] = packbf(p[14], p[15]);
        bf16x8 pfa = __builtin_bit_cast(bf16x8, fa);
        bf16x8 pfb = __builtin_bit_cast(bf16x8, fb);

        const short* vrow = vb + (size_t)il * 1024 + j0 + 4 * hi;
        bf16x8 vfa = cat4(*(const bf16x4*)(vrow),      *(const bf16x4*)(vrow + 8));
        bf16x8 vfb = cat4(*(const bf16x4*)(vrow + 16), *(const bf16x4*)(vrow + 24));

        oacc = MFMA32(vfa, pfa, oacc);
        oacc = MFMA32(vfb, pfb, oacc);
    }

    float tot = lrun + __shfl_xor(lrun, 32);
    if (hi == 0) lpart[((size_t)s * 64 + bh) * 1024 + ibase + il] = tot;

    short* obase = opart + (((size_t)s * 8 + b) * 256 + h * 32) * 1024 + ibase + il;
#pragma unroll
    for (int r = 0; r < 16; ++r) {
        int d = (r & 3) + 8 * (r >> 2) + 4 * hi;
        obase[(size_t)d * 1024] = f2b(oacc[r]);
    }
}

// ---------------------------------------------------------------------------
// K3: combine splits -> ao2[b][c][n], fused with per-(b,c) sum/sumsq (psum).
// One block per (b,c) row; thread owns 4 consecutive n's.
// ---------------------------------------------------------------------------
__global__ __launch_bounds__(256) void combine_k(const short* __restrict__ opart,
                                                 const float* __restrict__ lpart,
                                                 float* __restrict__ ao2,
                                                 float* __restrict__ p1,
                                                 float* __restrict__ p2) {
    int row = blockIdx.x;            // b*256 + c
    int b = row >> 8, c = row & 255, h = c >> 5;
    int t = threadIdx.x;
    int n0 = t * 4;

    float o[4] = {0.f, 0.f, 0.f, 0.f};
    float ls[4] = {0.f, 0.f, 0.f, 0.f};
#pragma unroll
    for (int s = 0; s < 4; ++s) {
        bf16x4 v = *(const bf16x4*)(opart + (((size_t)s * 8 + b) * 256 + c) * 1024 + n0);
#pragma unroll
        for (int j = 0; j < 4; ++j) o[j] += b2f(v[j]);
        float4 lv = *(const float4*)(lpart + ((size_t)s * 64 + b * 8 + h) * 1024 + n0);
        ls[0] += lv.x; ls[1] += lv.y; ls[2] += lv.z; ls[3] += lv.w;
    }
    float r0 = o[0] / ls[0], r1 = o[1] / ls[1], r2 = o[2] / ls[2], r3 = o[3] / ls[3];
    float4 out = {r0, r1, r2, r3};
    *(float4*)(ao2 + (size_t)row * 1024 + n0) = out;

    float ssum = r0 + r1 + r2 + r3;
    float qsum = r0 * r0 + r1 * r1 + r2 * r2 + r3 * r3;
#pragma unroll
    for (int off = 1; off < 64; off <<= 1) {
        ssum += __shfl_xor(ssum, off);
        qsum += __shfl_xor(qsum, off);
    }
    __shared__ float rs[4], rq[4];
    int lane = t & 63, wv = t >> 6;
    if (lane == 0) { rs[wv] = ssum; rq[wv] = qsum; }
    __syncthreads();
    if (t == 0) {
        p1[row] = rs[0] + rs[1] + rs[2] + rs[3];
        p2[row] = rq[0] + rq[1] + rq[2] + rq[3];
    }
}

// ---------------------------------------------------------------------------
// K4: per-batch LayerNorm stats (up never materialized)
// ---------------------------------------------------------------------------
__global__ __launch_bounds__(256) void stats_k(const float* __restrict__ p1,
                                               const float* __restrict__ p2,
                                               const float* __restrict__ wlp,
                                               const float* __restrict__ blp,
                                               float* __restrict__ stats) {
    int b = blockIdx.x, c = threadIdx.x;
    float s = p1[b * 256 + c];
    float q = p2[b * 256 + c];
    float w0 = wlp[c * 4], w1 = wlp[c * 4 + 1], w2 = wlp[c * 4 + 2], w3 = wlp[c * 4 + 3];
    float S1 = w0 + w1 + w2 + w3, S2 = w0 * w0 + w1 * w1 + w2 * w2 + w3 * w3;
    float bl = blp[c];
    float su = S1 * s + 4096.f * bl;
    float sq = S2 * q + 2.f * bl * S1 * s + 4096.f * bl * bl;
    __shared__ float rs_[256], rq_[256];
    rs_[c] = su; rq_[c] = sq;
    __syncthreads();
    for (int o = 128; o > 0; o >>= 1) {
        if (c < o) { rs_[c] += rs_[c + o]; rq_[c] += rq_[c + o]; }
        __syncthreads();
    }
    if (c == 0) {
        const float N = 1048576.f;
        float mu = rs_[0] / N;
        float var = rq_[0] / N - mu * mu;
        stats[b] = mu;
        stats[8 + b] = rsqrtf(var + 1e-5f);
    }
}

// ---------------------------------------------------------------------------
// K5: MFMA projection GEMM with fused upsample+LayerNorm B-operand.
// ---------------------------------------------------------------------------
__global__ __launch_bounds__(256) void proj_k(const float* __restrict__ ao2,
                                              const float* __restrict__ wp,
                                              const float* __restrict__ wlp,
                                              const float* __restrict__ blp,
                                              const float* __restrict__ gamma,
                                              const float* __restrict__ beta,
                                              const float* __restrict__ stats,
                                              float* __restrict__ y) {
    int b = blockIdx.z;
    int otile = blockIdx.y * 64;
    int mt = blockIdx.x;
    float mu = stats[b], rs = stats[8 + b];

    __shared__ short As[64][40];
    __shared__ short Bs[128][40];

    int t = threadIdx.x;
    int w = t >> 6, l = t & 63, g = l >> 4, li = l & 15;
    int oh = (w >> 1) * 32, mh = (w & 1) * 64;

    f32x4 zero = {0.f, 0.f, 0.f, 0.f};
    f32x4 acc[2][4];
#pragma unroll
    for (int og = 0; og < 2; ++og)
#pragma unroll
        for (int mg = 0; mg < 4; ++mg) acc[og][mg] = zero;

    int so = t >> 2, sc = (t & 3) * 8;
    int bc = t & 31, bm = (t >> 5) * 16;
    int p = t >> 7;
    int wbase = bm & 63;

    for (int kc = 0; kc < 256; kc += 32) {
        const float* wrow = wp + (size_t)(otile + so) * 256 + kc + sc;
#pragma unroll
        for (int j = 0; j < 8; ++j) As[so][sc + j] = f2b(wrow[j]);
        int c = kc + bc;
        float Ac = gamma[c] * rs;
        float Dc = Ac * (blp[c] - mu) + beta[c];
        float w0 = Ac * wlp[c * 4 + p * 2 + 0];
        float w1 = Ac * wlp[c * 4 + p * 2 + 1];
        const float* arow = ao2 + ((size_t)(b * 256 + c)) * 1024 + mt * 32 + (wbase >> 1);
        float4 a0 = *(const float4*)arow;
        float4 a1 = *(const float4*)(arow + 4);
        float av[8] = {a0.x, a0.y, a0.z, a0.w, a1.x, a1.y, a1.z, a1.w};
#pragma unroll
        for (int k = 0; k < 8; ++k) {
            Bs[bm + 2 * k    ][bc] = f2b(w0 * av[k] + Dc);
            Bs[bm + 2 * k + 1][bc] = f2b(w1 * av[k] + Dc);
        }
        __syncthreads();
        bf16x8 af[2], bf_[4];
#pragma unroll
        for (int og = 0; og < 2; ++og) af[og] = *(const bf16x8*)&As[oh + og * 16 + li][8 * g];
#pragma unroll
        for (int mg = 0; mg < 4; ++mg) bf_[mg] = *(const bf16x8*)&Bs[mh + mg * 16 + li][8 * g];
#pragma unroll
        for (int og = 0; og < 2; ++og)
#pragma unroll
            for (int mg = 0; mg < 4; ++mg) acc[og][mg] = MFMA16(af[og], bf_[mg], acc[og][mg]);
        __syncthreads();
    }

#pragma unroll
    for (int og = 0; og < 2; ++og) {
        int o = otile + oh + og * 16 + 4 * g;
#pragma unroll
        for (int mg = 0; mg < 4; ++mg) {
            int m = mt * 128 + mh + mg * 16 + li;
            float* yp = y + ((size_t)b * 256 + o) * 4096 + m;
#pragma unroll
            for (int r = 0; r < 4; ++r) yp[(size_t)r * 4096] = acc[og][mg][r];
        }
    }
}

extern "C" void kernel_launch(void* const* d_in, const int* in_sizes, int n_in,
                              void* d_out, int out_size, void* d_ws, size_t ws_size,
                              hipStream_t stream) {
    const float* x      = (const float*)d_in[0];
    const float* w_qkv  = (const float*)d_in[1];
    const float* w_lp   = (const float*)d_in[2];
    const float* b_lp   = (const float*)d_in[3];
    const float* gamma  = (const float*)d_in[4];
    const float* beta   = (const float*)d_in[5];
    const float* w_proj = (const float*)d_in[6];
    float* y = (float*)d_out;

    // d_out (16,777,216 shorts) as scratch. Lifetimes:
    //   xt, wbuf : dead after qkv_k
    //   opart/lpart (overlap xt+wbuf region): written by attn_k, dead after combine_k
    //   qt/kt/vv : dead after attn_k
    //   y overwrites everything at proj_k (last kernel).
    short* qt   = (short*)d_out;               // [0, 2097152)
    short* kt   = qt + 2097152;                // [2097152, 4194304)
    short* vv   = kt + 2097152;                // [4194304, 6291456)
    short* xt   = vv + 2097152;                // [6291456, 8388608)
    short* wbuf = xt + 2097152;                // [8388608, 8585216)
    short* opart = vv + 2097152;               // [6291456, 14680064) overlaps xt/wbuf (dead)
    float* lpart = (float*)((short*)d_out + 14680064);  // 262144 floats -> ends 15204352

    float* ao2   = (float*)d_ws;               // 2097152 floats [b][c][n]
    float* p1    = ao2 + 2097152;              // 2048
    float* p2    = p1 + 2048;                  // 2048
    float* stats = p2 + 2048;                  // 16

    wconv_k<<<96, 256, 0, stream>>>(w_qkv, wbuf);
    xt_k<<<dim3(32, 8), 256, 0, stream>>>(x, xt);
    qkv_k<<<dim3(8, 12, 8), 256, 0, stream>>>(wbuf, xt, qt, kt, vv);
    attn_k<<<dim3(8, 8, 32), 256, 0, stream>>>(qt, kt, vv, opart, lpart);
    combine_k<<<2048, 256, 0, stream>>>(opart, lpart, ao2, p1, p2);
    stats_k<<<8, 256, 0, stream>>>(p1, p2, w_lp, b_lp, stats);
    proj_k<<<dim3(32, 4, 8), 256, 0, stream>>>(ao2, w_proj, w_lp, b_lp, gamma, beta, stats, y);
}

// Round 7
// 92.176 us; speedup vs baseline: 1.1833x; 1.1833x over previous
//
#include <hip/hip_runtime.h>
#include <hip/hip_bf16.h>

// attention scale folded with log2(e): softmax exp(x) = exp2(x * log2e)
#define ATT_SCALE_L2E 0.2550322540f   // 32^-0.5 * log2(e)

typedef __attribute__((ext_vector_type(8))) short bf16x8;
typedef __attribute__((ext_vector_type(4))) short bf16x4;
typedef __attribute__((ext_vector_type(4))) float f32x4;
typedef __attribute__((ext_vector_type(16))) float f32x16;
typedef __attribute__((ext_vector_type(4))) int i32x4;

#define MFMA16(a, b, c) __builtin_amdgcn_mfma_f32_16x16x32_bf16(a, b, c, 0, 0, 0)
#define MFMA32(a, b, c) __builtin_amdgcn_mfma_f32_32x32x16_bf16(a, b, c, 0, 0, 0)

__device__ inline short f2b(float f) {
    return __builtin_bit_cast(short, __float2bfloat16(f));
}

__device__ inline bf16x8 cat4(bf16x4 a, bf16x4 b) {
    bf16x8 r;
    r[0] = a[0]; r[1] = a[1]; r[2] = a[2]; r[3] = a[3];
    r[4] = b[0]; r[5] = b[1]; r[6] = b[2]; r[7] = b[3];
    return r;
}

__device__ inline int packbf(float a, float b) {
    unsigned lo = (unsigned short)f2b(a);
    unsigned hi = (unsigned short)f2b(b);
    return (int)(lo | (hi << 16));
}

// ---------------------------------------------------------------------------
// K0a: w_qkv fp32 -> bf16
// ---------------------------------------------------------------------------
__global__ __launch_bounds__(256) void wconv_k(const float* __restrict__ w,
                                               short* __restrict__ wb) {
    int i0 = (blockIdx.x * 256 + threadIdx.x) * 8;
    float4 lo = *(const float4*)(w + i0);
    float4 hi = *(const float4*)(w + i0 + 4);
    bf16x8 o;
    o[0] = f2b(lo.x); o[1] = f2b(lo.y); o[2] = f2b(lo.z); o[3] = f2b(lo.w);
    o[4] = f2b(hi.x); o[5] = f2b(hi.y); o[6] = f2b(hi.z); o[7] = f2b(hi.w);
    *(bf16x8*)(wb + i0) = o;
}

// ---------------------------------------------------------------------------
// K0b: fused downsample + transpose + bf16: xt[b][n][c]
// ---------------------------------------------------------------------------
__global__ __launch_bounds__(256) void xt_k(const float* __restrict__ x,
                                            short* __restrict__ xt) {
    int b = blockIdx.y;
    int t = threadIdx.x;
    int n = blockIdx.x * 32 + (t >> 3);
    const float* xb = x + (size_t)b * 1048576 + (n >> 5) * 128 + (n & 31) * 2;
    short* dst = xt + ((size_t)b * 1024 + n) * 256;
#pragma unroll
    for (int it = 0; it < 4; ++it) {
        int c = (t & 7) * 8 + it * 64;
        bf16x8 o;
#pragma unroll
        for (int j = 0; j < 8; ++j) o[j] = f2b(xb[(size_t)(c + j) * 4096]);
        *(bf16x8*)(dst + c) = o;
    }
}

// ---------------------------------------------------------------------------
// K1: QKV MFMA GEMM (LDS-free main loop), epilogue transpose.
//   qt[bh][n][d] (q * scale*log2e), kt[bh][n][d],
//   vvr[bh][jb][q][hi][il][jj] = V[il][jb*32+q*8+4*hi+jj]  (attn-coalesced)
// ---------------------------------------------------------------------------
__global__ __launch_bounds__(256) void qkv_k(const short* __restrict__ wb,
                                             const short* __restrict__ xt,
                                             short* __restrict__ qt,
                                             short* __restrict__ kt,
                                             short* __restrict__ vvr) {
    int b = blockIdx.z;
    int otile = blockIdx.y * 64;
    int ntile = blockIdx.x * 128;
    int t = threadIdx.x;
    int w = t >> 6, l = t & 63, g = l >> 4, li = l & 15;
    int oh = (w & 1) * 32, mh = (w >> 1) * 64;
    int o_base = otile + oh;
    int head = o_base / 96;
    int role = (o_base >> 5) % 3;  // 0=q 1=k 2=v
    size_t bh = (size_t)b * 8 + head;

    const short* arow = wb + (size_t)o_base * 256;
    const short* brow = xt + ((size_t)b * 1024 + ntile + mh) * 256;

    f32x4 zero = {0.f, 0.f, 0.f, 0.f};
    f32x4 acc[2][4];
#pragma unroll
    for (int og = 0; og < 2; ++og)
#pragma unroll
        for (int mg = 0; mg < 4; ++mg) acc[og][mg] = zero;

#pragma unroll
    for (int kc = 0; kc < 256; kc += 32) {
        bf16x8 af[2], bf_[4];
#pragma unroll
        for (int og = 0; og < 2; ++og)
            af[og] = *(const bf16x8*)(arow + (size_t)(og * 16 + li) * 256 + kc + 8 * g);
#pragma unroll
        for (int mg = 0; mg < 4; ++mg)
            bf_[mg] = *(const bf16x8*)(brow + (size_t)(mg * 16 + li) * 256 + kc + 8 * g);
#pragma unroll
        for (int og = 0; og < 2; ++og)
#pragma unroll
            for (int mg = 0; mg < 4; ++mg)
                acc[og][mg] = MFMA16(af[og], bf_[mg], acc[og][mg]);
    }

    __shared__ short Tl[4][32][64];
    short (*Tw)[64] = Tl[w];
    float sc = (role == 0) ? ATT_SCALE_L2E : 1.f;

#pragma unroll
    for (int og = 0; og < 2; ++og)
#pragma unroll
        for (int mg = 0; mg < 4; ++mg)
#pragma unroll
            for (int r = 0; r < 4; ++r) {
                int op = og * 16 + 4 * g + r;
                int qp = (op >> 3) & 3;
                Tw[op][(mg * 16 + li) ^ (qp << 4)] = f2b(acc[og][mg][r] * sc);
            }
    __syncthreads();

    if (role == 2) {
        // write vvr: 8 iterations, 8B (4 consecutive j for one d) per lane
#pragma unroll
        for (int it = 0; it < 8; ++it) {
            int s = it * 64 + l;          // 0..511
            int d = s & 31;
            int n_rel = (s >> 5) * 4;     // 0..60, 4-aligned
            int n = ntile + mh + n_rel;
            int jb = n >> 5;
            int q = (n & 31) >> 3;
            int hi2 = (n & 7) >> 2;
            int q2 = (d >> 3) & 3;
            bf16x4 vo = *(const bf16x4*)&Tw[d][n_rel ^ (q2 << 4)];
            *(bf16x4*)(vvr + (size_t)bh * 32768 +
                       ((((size_t)jb * 4 + q) * 2 + hi2) * 32 + d) * 4) = vo;
        }
    } else {
        short* dst = (role == 0) ? qt : kt;
#pragma unroll
        for (int it = 0; it < 4; ++it) {
            int s = it * 64 + l;
            int dq = (l & 3) * 8;
            int n = s >> 2;
            int q2 = dq >> 3;
            bf16x8 vo;
#pragma unroll
            for (int j = 0; j < 8; ++j)
                vo[j] = Tw[dq + j][n ^ (q2 << 4)];
            *(bf16x8*)(dst + ((size_t)bh * 1024 + ntile + mh + n) * 32 + dq) = vo;
        }
    }
}

// ---------------------------------------------------------------------------
// K2: attention, swapped-QK^T 32x32 MFMA, P lane-local via rho-map (verified
// r5). V loads now fully coalesced via vvr layout. exp2f = native v_exp_f32
// (scale*log2e pre-folded into q). Output ao2[b][c][n], zero LDS.
// ---------------------------------------------------------------------------
__global__ __launch_bounds__(256) void attn_k(const short* __restrict__ qt,
                                              const short* __restrict__ kt,
                                              const short* __restrict__ vvr,
                                              float* __restrict__ ao2) {
    int b = blockIdx.z, h = blockIdx.y;
    int bh = b * 8 + h;
    int w = threadIdx.x >> 6, l = threadIdx.x & 63;
    int il = l & 31, hi = l >> 5;
    int ibase = blockIdx.x * 128 + w * 32;

    const short* qtb = qt + (size_t)bh * 32768;
    const short* ktb = kt + (size_t)bh * 32768;
    const short* vbase = vvr + (size_t)bh * 32768 + (hi * 32 + il) * 4;

    bf16x8 qf0 = *(const bf16x8*)(qtb + (size_t)(ibase + il) * 32 + 8 * hi);
    bf16x8 qf1 = *(const bf16x8*)(qtb + (size_t)(ibase + il) * 32 + 16 + 8 * hi);

    f32x16 zero16 = {0.f,0.f,0.f,0.f,0.f,0.f,0.f,0.f,0.f,0.f,0.f,0.f,0.f,0.f,0.f,0.f};
    f32x16 oacc = zero16;
    float lrun = 0.f;

#pragma unroll 2
    for (int jb = 0; jb < 32; ++jb) {
        int j0 = jb * 32;
        bf16x8 kf0 = *(const bf16x8*)(ktb + (size_t)(j0 + il) * 32 + 8 * hi);
        bf16x8 kf1 = *(const bf16x8*)(ktb + (size_t)(j0 + il) * 32 + 16 + 8 * hi);
        f32x16 s = MFMA32(kf0, qf0, zero16);
        s = MFMA32(kf1, qf1, s);

        float p[16];
#pragma unroll
        for (int r = 0; r < 16; ++r) {
            p[r] = exp2f(s[r]);
            lrun += p[r];
        }

        i32x4 fa, fb;
        fa[0] = packbf(p[0], p[1]);   fa[1] = packbf(p[2], p[3]);
        fa[2] = packbf(p[4], p[5]);   fa[3] = packbf(p[6], p[7]);
        fb[0] = packbf(p[8], p[9]);   fb[1] = packbf(p[10], p[11]);
        fb[2] = packbf(p[12], p[13]); fb[3] = packbf(p[14], p[15]);
        bf16x8 pfa = __builtin_bit_cast(bf16x8, fa);
        bf16x8 pfb = __builtin_bit_cast(bf16x8, fb);

        // coalesced V: 8B per lane, lane-major within each (jb,q) panel
        bf16x8 vfa = cat4(*(const bf16x4*)(vbase + (size_t)(jb * 4 + 0) * 256),
                          *(const bf16x4*)(vbase + (size_t)(jb * 4 + 1) * 256));
        bf16x8 vfb = cat4(*(const bf16x4*)(vbase + (size_t)(jb * 4 + 2) * 256),
                          *(const bf16x4*)(vbase + (size_t)(jb * 4 + 3) * 256));

        oacc = MFMA32(vfa, pfa, oacc);
        oacc = MFMA32(vfb, pfb, oacc);
    }

    float tot = lrun + __shfl_xor(lrun, 32);
    float inv = 1.f / tot;

    float* base = ao2 + ((size_t)(b * 256 + h * 32)) * 1024 + ibase + il;
#pragma unroll
    for (int r = 0; r < 16; ++r) {
        int d = (r & 3) + 8 * (r >> 2) + 4 * hi;
        base[(size_t)d * 1024] = oacc[r] * inv;
    }
}

// ---------------------------------------------------------------------------
// K3: per-(b,c) sum/sumsq of ao2 rows (contiguous 1024 floats). 1 wave/row.
// ---------------------------------------------------------------------------
__global__ __launch_bounds__(64) void psum_k(const float* __restrict__ ao2,
                                             float* __restrict__ p1,
                                             float* __restrict__ p2) {
    int row = blockIdx.x;
    const float* base = ao2 + (size_t)row * 1024;
    int l = threadIdx.x;
    float s = 0.f, q = 0.f;
#pragma unroll
    for (int t = 0; t < 4; ++t) {
        float4 v = *(const float4*)(base + l * 4 + t * 256);
        s += v.x + v.y + v.z + v.w;
        q += v.x * v.x + v.y * v.y + v.z * v.z + v.w * v.w;
    }
#pragma unroll
    for (int o = 1; o < 64; o <<= 1) {
        s += __shfl_xor(s, o);
        q += __shfl_xor(q, o);
    }
    if (l == 0) { p1[row] = s; p2[row] = q; }
}

// ---------------------------------------------------------------------------
// K4: per-batch LayerNorm stats (up never materialized)
// ---------------------------------------------------------------------------
__global__ __launch_bounds__(256) void stats_k(const float* __restrict__ p1,
                                               const float* __restrict__ p2,
                                               const float* __restrict__ wlp,
                                               const float* __restrict__ blp,
                                               float* __restrict__ stats) {
    int b = blockIdx.x, c = threadIdx.x;
    float s = p1[b * 256 + c];
    float q = p2[b * 256 + c];
    float w0 = wlp[c * 4], w1 = wlp[c * 4 + 1], w2 = wlp[c * 4 + 2], w3 = wlp[c * 4 + 3];
    float S1 = w0 + w1 + w2 + w3, S2 = w0 * w0 + w1 * w1 + w2 * w2 + w3 * w3;
    float bl = blp[c];
    float su = S1 * s + 4096.f * bl;
    float sq = S2 * q + 2.f * bl * S1 * s + 4096.f * bl * bl;
    __shared__ float rs_[256], rq_[256];
    rs_[c] = su; rq_[c] = sq;
    __syncthreads();
    for (int o = 128; o > 0; o >>= 1) {
        if (c < o) { rs_[c] += rs_[c + o]; rq_[c] += rq_[c + o]; }
        __syncthreads();
    }
    if (c == 0) {
        const float N = 1048576.f;
        float mu = rs_[0] / N;
        float var = rq_[0] / N - mu * mu;
        stats[b] = mu;
        stats[8 + b] = rsqrtf(var + 1e-5f);
    }
}

// ---------------------------------------------------------------------------
// K5: MFMA projection GEMM with fused upsample+LayerNorm B-operand.
// ---------------------------------------------------------------------------
__global__ __launch_bounds__(256) void proj_k(const float* __restrict__ ao2,
                                              const float* __restrict__ wp,
                                              const float* __restrict__ wlp,
                                              const float* __restrict__ blp,
                                              const float* __restrict__ gamma,
                                              const float* __restrict__ beta,
                                              const float* __restrict__ stats,
                                              float* __restrict__ y) {
    int b = blockIdx.z;
    int otile = blockIdx.y * 64;
    int mt = blockIdx.x;
    float mu = stats[b], rs = stats[8 + b];

    __shared__ short As[64][40];
    __shared__ short Bs[128][40];

    int t = threadIdx.x;
    int w = t >> 6, l = t & 63, g = l >> 4, li = l & 15;
    int oh = (w >> 1) * 32, mh = (w & 1) * 64;

    f32x4 zero = {0.f, 0.f, 0.f, 0.f};
    f32x4 acc[2][4];
#pragma unroll
    for (int og = 0; og < 2; ++og)
#pragma unroll
        for (int mg = 0; mg < 4; ++mg) acc[og][mg] = zero;

    int so = t >> 2, sc = (t & 3) * 8;
    int bc = t & 31, bm = (t >> 5) * 16;
    int p = t >> 7;
    int wbase = bm & 63;

    for (int kc = 0; kc < 256; kc += 32) {
        const float* wrow = wp + (size_t)(otile + so) * 256 + kc + sc;
#pragma unroll
        for (int j = 0; j < 8; ++j) As[so][sc + j] = f2b(wrow[j]);
        int c = kc + bc;
        float Ac = gamma[c] * rs;
        float Dc = Ac * (blp[c] - mu) + beta[c];
        float w0 = Ac * wlp[c * 4 + p * 2 + 0];
        float w1 = Ac * wlp[c * 4 + p * 2 + 1];
        const float* arow = ao2 + ((size_t)(b * 256 + c)) * 1024 + mt * 32 + (wbase >> 1);
        float4 a0 = *(const float4*)arow;
        float4 a1 = *(const float4*)(arow + 4);
        float av[8] = {a0.x, a0.y, a0.z, a0.w, a1.x, a1.y, a1.z, a1.w};
#pragma unroll
        for (int k = 0; k < 8; ++k) {
            Bs[bm + 2 * k    ][bc] = f2b(w0 * av[k] + Dc);
            Bs[bm + 2 * k + 1][bc] = f2b(w1 * av[k] + Dc);
        }
        __syncthreads();
        bf16x8 af[2], bf_[4];
#pragma unroll
        for (int og = 0; og < 2; ++og) af[og] = *(const bf16x8*)&As[oh + og * 16 + li][8 * g];
#pragma unroll
        for (int mg = 0; mg < 4; ++mg) bf_[mg] = *(const bf16x8*)&Bs[mh + mg * 16 + li][8 * g];
#pragma unroll
        for (int og = 0; og < 2; ++og)
#pragma unroll
            for (int mg = 0; mg < 4; ++mg) acc[og][mg] = MFMA16(af[og], bf_[mg], acc[og][mg]);
        __syncthreads();
    }

#pragma unroll
    for (int og = 0; og < 2; ++og) {
        int o = otile + oh + og * 16 + 4 * g;
#pragma unroll
        for (int mg = 0; mg < 4; ++mg) {
            int m = mt * 128 + mh + mg * 16 + li;
            float* yp = y + ((size_t)b * 256 + o) * 4096 + m;
#pragma unroll
            for (int r = 0; r < 4; ++r) yp[(size_t)r * 4096] = acc[og][mg][r];
        }
    }
}

extern "C" void kernel_launch(void* const* d_in, const int* in_sizes, int n_in,
                              void* d_out, int out_size, void* d_ws, size_t ws_size,
                              hipStream_t stream) {
    const float* x      = (const float*)d_in[0];
    const float* w_qkv  = (const float*)d_in[1];
    const float* w_lp   = (const float*)d_in[2];
    const float* b_lp   = (const float*)d_in[3];
    const float* gamma  = (const float*)d_in[4];
    const float* beta   = (const float*)d_in[5];
    const float* w_proj = (const float*)d_in[6];
    float* y = (float*)d_out;

    short* qt   = (short*)d_out;        // 2097152 shorts
    short* kt   = qt + 2097152;
    short* vvr  = kt + 2097152;
    short* xt   = vvr + 2097152;
    short* wbuf = xt + 2097152;

    float* ao2   = (float*)d_ws;        // 2097152 floats [b][c][n]
    float* p1    = ao2 + 2097152;       // 2048
    float* p2    = p1 + 2048;           // 2048
    float* stats = p2 + 2048;           // 16

    wconv_k<<<96, 256, 0, stream>>>(w_qkv, wbuf);
    xt_k<<<dim3(32, 8), 256, 0, stream>>>(x, xt);
    qkv_k<<<dim3(8, 12, 8), 256, 0, stream>>>(wbuf, xt, qt, kt, vvr);
    attn_k<<<dim3(8, 8, 8), 256, 0, stream>>>(qt, kt, vvr, ao2);
    psum_k<<<2048, 64, 0, stream>>>(ao2, p1, p2);
    stats_k<<<8, 256, 0, stream>>>(p1, p2, w_lp, b_lp, stats);
    proj_k<<<dim3(32, 4, 8), 256, 0, stream>>>(ao2, w_proj, w_lp, b_lp, gamma, beta, stats, y);
}

// Round 8
// 86.074 us; speedup vs baseline: 1.2671x; 1.0709x over previous
//
#include <hip/hip_runtime.h>
#include <hip/hip_bf16.h>

// attention scale folded with log2(e): softmax exp(x) = exp2(x * log2e)
#define ATT_SCALE_L2E 0.2550322540f   // 32^-0.5 * log2(e)

typedef __attribute__((ext_vector_type(8))) short bf16x8;
typedef __attribute__((ext_vector_type(4))) short bf16x4;
typedef __attribute__((ext_vector_type(4))) float f32x4;
typedef __attribute__((ext_vector_type(16))) float f32x16;
typedef __attribute__((ext_vector_type(4))) int i32x4;

#define MFMA16(a, b, c) __builtin_amdgcn_mfma_f32_16x16x32_bf16(a, b, c, 0, 0, 0)
#define MFMA32(a, b, c) __builtin_amdgcn_mfma_f32_32x32x16_bf16(a, b, c, 0, 0, 0)

__device__ inline short f2b(float f) {
    return __builtin_bit_cast(short, __float2bfloat16(f));
}

__device__ inline bf16x8 cat4(bf16x4 a, bf16x4 b) {
    bf16x8 r;
    r[0] = a[0]; r[1] = a[1]; r[2] = a[2]; r[3] = a[3];
    r[4] = b[0]; r[5] = b[1]; r[6] = b[2]; r[7] = b[3];
    return r;
}

// packed f32x2 -> bf16x2 in one instruction (D[15:0]=bf16(S0), D[31:16]=bf16(S1))
__device__ inline int cvt_pk(float a, float b) {
    int r;
    asm("v_cvt_pk_bf16_f32 %0, %1, %2" : "=v"(r) : "v"(a), "v"(b));
    return r;
}

// ---------------------------------------------------------------------------
// K0a: w_qkv fp32 -> bf16
// ---------------------------------------------------------------------------
__global__ __launch_bounds__(256) void wconv_k(const float* __restrict__ w,
                                               short* __restrict__ wb) {
    int i0 = (blockIdx.x * 256 + threadIdx.x) * 8;
    float4 lo = *(const float4*)(w + i0);
    float4 hi = *(const float4*)(w + i0 + 4);
    bf16x8 o;
    o[0] = f2b(lo.x); o[1] = f2b(lo.y); o[2] = f2b(lo.z); o[3] = f2b(lo.w);
    o[4] = f2b(hi.x); o[5] = f2b(hi.y); o[6] = f2b(hi.z); o[7] = f2b(hi.w);
    *(bf16x8*)(wb + i0) = o;
}

// ---------------------------------------------------------------------------
// K0b: fused downsample + transpose + bf16: xt[b][n][c]
// ---------------------------------------------------------------------------
__global__ __launch_bounds__(256) void xt_k(const float* __restrict__ x,
                                            short* __restrict__ xt) {
    int b = blockIdx.y;
    int t = threadIdx.x;
    int n = blockIdx.x * 32 + (t >> 3);
    const float* xb = x + (size_t)b * 1048576 + (n >> 5) * 128 + (n & 31) * 2;
    short* dst = xt + ((size_t)b * 1024 + n) * 256;
#pragma unroll
    for (int it = 0; it < 4; ++it) {
        int c = (t & 7) * 8 + it * 64;
        bf16x8 o;
#pragma unroll
        for (int j = 0; j < 8; ++j) o[j] = f2b(xb[(size_t)(c + j) * 4096]);
        *(bf16x8*)(dst + c) = o;
    }
}

// ---------------------------------------------------------------------------
// K1: QKV MFMA GEMM (LDS-free main loop), epilogue transpose.
// Grid (b, ntile, otile): linear%8 = b -> per-XCD xt[b] locality.
// ---------------------------------------------------------------------------
__global__ __launch_bounds__(256) void qkv_k(const short* __restrict__ wb,
                                             const short* __restrict__ xt,
                                             short* __restrict__ qt,
                                             short* __restrict__ kt,
                                             short* __restrict__ vvr) {
    int b = blockIdx.x;
    int ntile = blockIdx.y * 128;
    int otile = blockIdx.z * 64;
    int t = threadIdx.x;
    int w = t >> 6, l = t & 63, g = l >> 4, li = l & 15;
    int oh = (w & 1) * 32, mh = (w >> 1) * 64;
    int o_base = otile + oh;
    int head = o_base / 96;
    int role = (o_base >> 5) % 3;  // 0=q 1=k 2=v
    size_t bh = (size_t)b * 8 + head;

    const short* arow = wb + (size_t)o_base * 256;
    const short* brow = xt + ((size_t)b * 1024 + ntile + mh) * 256;

    f32x4 zero = {0.f, 0.f, 0.f, 0.f};
    f32x4 acc[2][4];
#pragma unroll
    for (int og = 0; og < 2; ++og)
#pragma unroll
        for (int mg = 0; mg < 4; ++mg) acc[og][mg] = zero;

#pragma unroll
    for (int kc = 0; kc < 256; kc += 32) {
        bf16x8 af[2], bf_[4];
#pragma unroll
        for (int og = 0; og < 2; ++og)
            af[og] = *(const bf16x8*)(arow + (size_t)(og * 16 + li) * 256 + kc + 8 * g);
#pragma unroll
        for (int mg = 0; mg < 4; ++mg)
            bf_[mg] = *(const bf16x8*)(brow + (size_t)(mg * 16 + li) * 256 + kc + 8 * g);
#pragma unroll
        for (int og = 0; og < 2; ++og)
#pragma unroll
            for (int mg = 0; mg < 4; ++mg)
                acc[og][mg] = MFMA16(af[og], bf_[mg], acc[og][mg]);
    }

    __shared__ short Tl[4][32][64];
    short (*Tw)[64] = Tl[w];
    float sc = (role == 0) ? ATT_SCALE_L2E : 1.f;

#pragma unroll
    for (int og = 0; og < 2; ++og)
#pragma unroll
        for (int mg = 0; mg < 4; ++mg)
#pragma unroll
            for (int r = 0; r < 4; ++r) {
                int op = og * 16 + 4 * g + r;
                int qp = (op >> 3) & 3;
                Tw[op][(mg * 16 + li) ^ (qp << 4)] = f2b(acc[og][mg][r] * sc);
            }
    __syncthreads();

    if (role == 2) {
        // write vvr[bh][jb][q][hi][il][jj] = V[d=il][jb*32+q*8+4*hi+jj]
#pragma unroll
        for (int it = 0; it < 8; ++it) {
            int s = it * 64 + l;          // 0..511
            int d = s & 31;
            int n_rel = (s >> 5) * 4;     // 0..60, 4-aligned
            int n = ntile + mh + n_rel;
            int jb = n >> 5;
            int q = (n & 31) >> 3;
            int hi2 = (n & 7) >> 2;
            int q2 = (d >> 3) & 3;
            bf16x4 vo = *(const bf16x4*)&Tw[d][n_rel ^ (q2 << 4)];
            *(bf16x4*)(vvr + (size_t)bh * 32768 +
                       ((((size_t)jb * 4 + q) * 2 + hi2) * 32 + d) * 4) = vo;
        }
    } else {
        short* dst = (role == 0) ? qt : kt;
#pragma unroll
        for (int it = 0; it < 4; ++it) {
            int s = it * 64 + l;
            int dq = (l & 3) * 8;
            int n = s >> 2;
            int q2 = dq >> 3;
            bf16x8 vo;
#pragma unroll
            for (int j = 0; j < 8; ++j)
                vo[j] = Tw[dq + j][n ^ (q2 << 4)];
            *(bf16x8*)(dst + ((size_t)bh * 1024 + ntile + mh + n) * 32 + dq) = vo;
        }
    }
}

// ---------------------------------------------------------------------------
// K2: attention, swapped-QK^T 32x32 MFMA, P lane-local via rho-map (verified
// r5). Grid (bh, itile): linear%8 = h -> all blocks sharing a head's K/V on
// one XCD (L2-resident ~1.5MB). cvt_pk packing (1 inst / 2 values).
// Output ao2[b][c][n], zero LDS.
// ---------------------------------------------------------------------------
__global__ __launch_bounds__(256) void attn_k(const short* __restrict__ qt,
                                              const short* __restrict__ kt,
                                              const short* __restrict__ vvr,
                                              float* __restrict__ ao2) {
    int bh = blockIdx.x;
    int b = bh >> 3, h = bh & 7;
    int w = threadIdx.x >> 6, l = threadIdx.x & 63;
    int il = l & 31, hi = l >> 5;
    int ibase = blockIdx.y * 128 + w * 32;

    const short* qtb = qt + (size_t)bh * 32768;
    const short* ktb = kt + (size_t)bh * 32768;
    const short* vbase = vvr + (size_t)bh * 32768 + (hi * 32 + il) * 4;

    bf16x8 qf0 = *(const bf16x8*)(qtb + (size_t)(ibase + il) * 32 + 8 * hi);
    bf16x8 qf1 = *(const bf16x8*)(qtb + (size_t)(ibase + il) * 32 + 16 + 8 * hi);

    f32x16 zero16 = {0.f,0.f,0.f,0.f,0.f,0.f,0.f,0.f,0.f,0.f,0.f,0.f,0.f,0.f,0.f,0.f};
    f32x16 oacc = zero16;
    float lrun = 0.f;

#pragma unroll 2
    for (int jb = 0; jb < 32; ++jb) {
        int j0 = jb * 32;
        bf16x8 kf0 = *(const bf16x8*)(ktb + (size_t)(j0 + il) * 32 + 8 * hi);
        bf16x8 kf1 = *(const bf16x8*)(ktb + (size_t)(j0 + il) * 32 + 16 + 8 * hi);
        f32x16 s = MFMA32(kf0, qf0, zero16);
        s = MFMA32(kf1, qf1, s);

        float p[16];
#pragma unroll
        for (int r = 0; r < 16; ++r) {
            p[r] = exp2f(s[r]);
            lrun += p[r];
        }

        i32x4 fa, fb;
        fa[0] = cvt_pk(p[0], p[1]);   fa[1] = cvt_pk(p[2], p[3]);
        fa[2] = cvt_pk(p[4], p[5]);   fa[3] = cvt_pk(p[6], p[7]);
        fb[0] = cvt_pk(p[8], p[9]);   fb[1] = cvt_pk(p[10], p[11]);
        fb[2] = cvt_pk(p[12], p[13]); fb[3] = cvt_pk(p[14], p[15]);
        bf16x8 pfa = __builtin_bit_cast(bf16x8, fa);
        bf16x8 pfb = __builtin_bit_cast(bf16x8, fb);

        // coalesced V: 8B per lane, lane-major within each (jb,q) panel
        bf16x8 vfa = cat4(*(const bf16x4*)(vbase + (size_t)(jb * 4 + 0) * 256),
                          *(const bf16x4*)(vbase + (size_t)(jb * 4 + 1) * 256));
        bf16x8 vfb = cat4(*(const bf16x4*)(vbase + (size_t)(jb * 4 + 2) * 256),
                          *(const bf16x4*)(vbase + (size_t)(jb * 4 + 3) * 256));

        oacc = MFMA32(vfa, pfa, oacc);
        oacc = MFMA32(vfb, pfb, oacc);
    }

    float tot = lrun + __shfl_xor(lrun, 32);
    float inv = 1.f / tot;

    float* base = ao2 + ((size_t)(b * 256 + h * 32)) * 1024 + ibase + il;
#pragma unroll
    for (int r = 0; r < 16; ++r) {
        int d = (r & 3) + 8 * (r >> 2) + 4 * hi;
        base[(size_t)d * 1024] = oacc[r] * inv;
    }
}

// ---------------------------------------------------------------------------
// K3: per-(b,c) sum/sumsq of ao2 rows (contiguous 1024 floats). 1 wave/row.
// ---------------------------------------------------------------------------
__global__ __launch_bounds__(64) void psum_k(const float* __restrict__ ao2,
                                             float* __restrict__ p1,
                                             float* __restrict__ p2) {
    int row = blockIdx.x;
    const float* base = ao2 + (size_t)row * 1024;
    int l = threadIdx.x;
    float s = 0.f, q = 0.f;
#pragma unroll
    for (int t = 0; t < 4; ++t) {
        float4 v = *(const float4*)(base + l * 4 + t * 256);
        s += v.x + v.y + v.z + v.w;
        q += v.x * v.x + v.y * v.y + v.z * v.z + v.w * v.w;
    }
#pragma unroll
    for (int o = 1; o < 64; o <<= 1) {
        s += __shfl_xor(s, o);
        q += __shfl_xor(q, o);
    }
    if (l == 0) { p1[row] = s; p2[row] = q; }
}

// ---------------------------------------------------------------------------
// K4: per-batch LayerNorm stats (up never materialized)
// ---------------------------------------------------------------------------
__global__ __launch_bounds__(256) void stats_k(const float* __restrict__ p1,
                                               const float* __restrict__ p2,
                                               const float* __restrict__ wlp,
                                               const float* __restrict__ blp,
                                               float* __restrict__ stats) {
    int b = blockIdx.x, c = threadIdx.x;
    float s = p1[b * 256 + c];
    float q = p2[b * 256 + c];
    float w0 = wlp[c * 4], w1 = wlp[c * 4 + 1], w2 = wlp[c * 4 + 2], w3 = wlp[c * 4 + 3];
    float S1 = w0 + w1 + w2 + w3, S2 = w0 * w0 + w1 * w1 + w2 * w2 + w3 * w3;
    float bl = blp[c];
    float su = S1 * s + 4096.f * bl;
    float sq = S2 * q + 2.f * bl * S1 * s + 4096.f * bl * bl;
    __shared__ float rs_[256], rq_[256];
    rs_[c] = su; rq_[c] = sq;
    __syncthreads();
    for (int o = 128; o > 0; o >>= 1) {
        if (c < o) { rs_[c] += rs_[c + o]; rq_[c] += rq_[c + o]; }
        __syncthreads();
    }
    if (c == 0) {
        const float N = 1048576.f;
        float mu = rs_[0] / N;
        float var = rq_[0] / N - mu * mu;
        stats[b] = mu;
        stats[8 + b] = rsqrtf(var + 1e-5f);
    }
}

// ---------------------------------------------------------------------------
// K5: MFMA projection GEMM with fused upsample+LayerNorm B-operand.
// Grid (b, mt, otile): linear%8 = b -> per-XCD ao2[b] locality.
// ---------------------------------------------------------------------------
__global__ __launch_bounds__(256) void proj_k(const float* __restrict__ ao2,
                                              const float* __restrict__ wp,
                                              const float* __restrict__ wlp,
                                              const float* __restrict__ blp,
                                              const float* __restrict__ gamma,
                                              const float* __restrict__ beta,
                                              const float* __restrict__ stats,
                                              float* __restrict__ y) {
    int b = blockIdx.x;
    int mt = blockIdx.y;
    int otile = blockIdx.z * 64;
    float mu = stats[b], rs = stats[8 + b];

    __shared__ short As[64][40];
    __shared__ short Bs[128][40];

    int t = threadIdx.x;
    int w = t >> 6, l = t & 63, g = l >> 4, li = l & 15;
    int oh = (w >> 1) * 32, mh = (w & 1) * 64;

    f32x4 zero = {0.f, 0.f, 0.f, 0.f};
    f32x4 acc[2][4];
#pragma unroll
    for (int og = 0; og < 2; ++og)
#pragma unroll
        for (int mg = 0; mg < 4; ++mg) acc[og][mg] = zero;

    int so = t >> 2, sc = (t & 3) * 8;
    int bc = t & 31, bm = (t >> 5) * 16;
    int p = t >> 7;
    int wbase = bm & 63;

    for (int kc = 0; kc < 256; kc += 32) {
        const float* wrow = wp + (size_t)(otile + so) * 256 + kc + sc;
#pragma unroll
        for (int j = 0; j < 8; ++j) As[so][sc + j] = f2b(wrow[j]);
        int c = kc + bc;
        float Ac = gamma[c] * rs;
        float Dc = Ac * (blp[c] - mu) + beta[c];
        float w0 = Ac * wlp[c * 4 + p * 2 + 0];
        float w1 = Ac * wlp[c * 4 + p * 2 + 1];
        const float* arow = ao2 + ((size_t)(b * 256 + c)) * 1024 + mt * 32 + (wbase >> 1);
        float4 a0 = *(const float4*)arow;
        float4 a1 = *(const float4*)(arow + 4);
        float av[8] = {a0.x, a0.y, a0.z, a0.w, a1.x, a1.y, a1.z, a1.w};
#pragma unroll
        for (int k = 0; k < 8; ++k) {
            Bs[bm + 2 * k    ][bc] = f2b(w0 * av[k] + Dc);
            Bs[bm + 2 * k + 1][bc] = f2b(w1 * av[k] + Dc);
        }
        __syncthreads();
        bf16x8 af[2], bf_[4];
#pragma unroll
        for (int og = 0; og < 2; ++og) af[og] = *(const bf16x8*)&As[oh + og * 16 + li][8 * g];
#pragma unroll
        for (int mg = 0; mg < 4; ++mg) bf_[mg] = *(const bf16x8*)&Bs[mh + mg * 16 + li][8 * g];
#pragma unroll
        for (int og = 0; og < 2; ++og)
#pragma unroll
            for (int mg = 0; mg < 4; ++mg) acc[og][mg] = MFMA16(af[og], bf_[mg], acc[og][mg]);
        __syncthreads();
    }

#pragma unroll
    for (int og = 0; og < 2; ++og) {
        int o = otile + oh + og * 16 + 4 * g;
#pragma unroll
        for (int mg = 0; mg < 4; ++mg) {
            int m = mt * 128 + mh + mg * 16 + li;
            float* yp = y + ((size_t)b * 256 + o) * 4096 + m;
#pragma unroll
            for (int r = 0; r < 4; ++r) yp[(size_t)r * 4096] = acc[og][mg][r];
        }
    }
}

extern "C" void kernel_launch(void* const* d_in, const int* in_sizes, int n_in,
                              void* d_out, int out_size, void* d_ws, size_t ws_size,
                              hipStream_t stream) {
    const float* x      = (const float*)d_in[0];
    const float* w_qkv  = (const float*)d_in[1];
    const float* w_lp   = (const float*)d_in[2];
    const float* b_lp   = (const float*)d_in[3];
    const float* gamma  = (const float*)d_in[4];
    const float* beta   = (const float*)d_in[5];
    const float* w_proj = (const float*)d_in[6];
    float* y = (float*)d_out;

    short* qt   = (short*)d_out;        // 2097152 shorts
    short* kt   = qt + 2097152;
    short* vvr  = kt + 2097152;
    short* xt   = vvr + 2097152;
    short* wbuf = xt + 2097152;

    float* ao2   = (float*)d_ws;        // 2097152 floats [b][c][n]
    float* p1    = ao2 + 2097152;       // 2048
    float* p2    = p1 + 2048;           // 2048
    float* stats = p2 + 2048;           // 16

    wconv_k<<<96, 256, 0, stream>>>(w_qkv, wbuf);
    xt_k<<<dim3(32, 8), 256, 0, stream>>>(x, xt);
    qkv_k<<<dim3(8, 8, 12), 256, 0, stream>>>(wbuf, xt, qt, kt, vvr);
    attn_k<<<dim3(64, 8), 256, 0, stream>>>(qt, kt, vvr, ao2);
    psum_k<<<2048, 64, 0, stream>>>(ao2, p1, p2);
    stats_k<<<8, 256, 0, stream>>>(p1, p2, w_lp, b_lp, stats);
    proj_k<<<dim3(8, 32, 4), 256, 0, stream>>>(ao2, w_proj, w_lp, b_lp, gamma, beta, stats, y);
}